// Round 8
// baseline (305.591 us; speedup 1.0000x reference)
//
#include <hip/hip_runtime.h>

typedef unsigned short u16;
typedef __attribute__((ext_vector_type(8))) short short8v;
typedef __attribute__((ext_vector_type(4))) float floatx4;

#define B_ 16
#define C_ 512
#define N_ 4096
#define K_ 128   // keys

__device__ __forceinline__ float bf2f(u16 u) {
    unsigned int x = ((unsigned int)u) << 16;
    return __builtin_bit_cast(float, x);
}
__device__ __forceinline__ u16 f2bf(float f) {
    unsigned int u = __builtin_bit_cast(unsigned int, f);
    u = u + 0x7FFFu + ((u >> 16) & 1u);
    return (u16)(u >> 16);
}

// ---------------------------------------------------------------------------
// P0: fp32 -> bf16 converts (y1,y2,wk1,wk2,wv1,wv2) + wq transpose, one launch
// ---------------------------------------------------------------------------
__global__ void conv_all(const float* __restrict__ y1, const float* __restrict__ y2,
                         const float* __restrict__ wk1, const float* __restrict__ wk2,
                         const float* __restrict__ wv1, const float* __restrict__ wv2,
                         const float* __restrict__ wq1, const float* __restrict__ wq2,
                         u16* y1b, u16* y2b, u16* wk1b, u16* wk2b, u16* wv1b, u16* wv2b,
                         u16* wq1t, u16* wq2t) {
    int tid = blockIdx.x * 256 + threadIdx.x;
    const int SY = B_ * K_ * C_;        // 1048576
    const int SWK = 256 * 512;          // 131072
    const int SWV = 512 * 512;          // 262144
    const int SQ = 128 * 512;           // 65536
    int base = 2*SY + 2*SWK + 2*SWV;
    if (tid < base) {
        const float* src; u16* dst; int off;
        if (tid < SY)                 { src = y1;  dst = y1b;  off = tid; }
        else if (tid < 2*SY)          { src = y2;  dst = y2b;  off = tid - SY; }
        else if (tid < 2*SY+SWK)      { src = wk1; dst = wk1b; off = tid - 2*SY; }
        else if (tid < 2*SY+2*SWK)    { src = wk2; dst = wk2b; off = tid - 2*SY - SWK; }
        else if (tid < 2*SY+2*SWK+SWV){ src = wv1; dst = wv1b; off = tid - 2*SY - 2*SWK; }
        else                          { src = wv2; dst = wv2b; off = tid - 2*SY - 2*SWK - SWV; }
        dst[off] = f2bf(src[off]);
    } else {
        int e = tid - base;           // 0 .. 2*SQ-1
        const float* s = (e >= SQ) ? wq2 : wq1;
        u16* d = (e >= SQ) ? wq2t : wq1t;
        e &= (SQ - 1);
        int dd = e >> 9;              // 0..127
        int c = e & 511;              // coalesced read over c
        d[c * 128 + dd] = f2bf(s[dd * 512 + c]);
    }
}

// ---------------------------------------------------------------------------
// P1 fused: kd[b][key][256] = y1@wk1^T - y2@wk2^T + (bk1-bk2)   (128 blocks)
//           vt1/vt2 [b][c][128] = (y@wv^T+bv)^T                 (512 blocks)
// flat grid 640 blocks x 64 threads
// ---------------------------------------------------------------------------
__global__ void gemm_gkdgv(const u16* __restrict__ y1b, const u16* __restrict__ y2b,
                           const u16* __restrict__ wk1b, const u16* __restrict__ wk2b,
                           const u16* __restrict__ wv1b, const u16* __restrict__ wv2b,
                           const float* __restrict__ bk1, const float* __restrict__ bk2,
                           const float* __restrict__ bv1, const float* __restrict__ bv2,
                           u16* kd, u16* vt1, u16* vt2) {
    int l = threadIdx.x;
    int id = blockIdx.x;
    if (id < 128) {
        // ---- kd: dual-accumulator GEMM
        int b = id >> 3, r = id & 7;
        int m0 = (r & 1) * 64;        // key tile
        int n0 = (r >> 1) * 64;       // d tile
        const u16* A1 = y1b + (size_t)b * K_ * C_;
        const u16* A2 = y2b + (size_t)b * K_ * C_;
        u16* outp = kd + (size_t)b * K_ * 256;
        floatx4 acc1[4][4] = {}, acc2[4][4] = {};
        for (int ch = 0; ch < 16; ++ch) {
            int koff = ch * 32 + (l >> 4) * 8;
            short8v a1[4], a2[4], w1[4], w2[4];
#pragma unroll
            for (int mf = 0; mf < 4; ++mf) {
                size_t ro = (size_t)(m0 + mf*16 + (l & 15)) * 512 + koff;
                a1[mf] = *(const short8v*)(A1 + ro);
                a2[mf] = *(const short8v*)(A2 + ro);
            }
#pragma unroll
            for (int nf = 0; nf < 4; ++nf) {
                size_t ro = (size_t)(n0 + nf*16 + (l & 15)) * 512 + koff;
                w1[nf] = *(const short8v*)(wk1b + ro);
                w2[nf] = *(const short8v*)(wk2b + ro);
            }
#pragma unroll
            for (int mf = 0; mf < 4; ++mf)
#pragma unroll
                for (int nf = 0; nf < 4; ++nf) {
                    acc1[mf][nf] = __builtin_amdgcn_mfma_f32_16x16x32_bf16(a1[mf], w1[nf], acc1[mf][nf], 0, 0, 0);
                    acc2[mf][nf] = __builtin_amdgcn_mfma_f32_16x16x32_bf16(a2[mf], w2[nf], acc2[mf][nf], 0, 0, 0);
                }
        }
#pragma unroll
        for (int mf = 0; mf < 4; ++mf)
#pragma unroll
            for (int nf = 0; nf < 4; ++nf)
#pragma unroll
                for (int rg = 0; rg < 4; ++rg) {
                    int m = m0 + mf*16 + (l >> 4)*4 + rg;
                    int n = n0 + nf*16 + (l & 15);
                    outp[(size_t)m * 256 + n] = f2bf(acc1[mf][nf][rg] - acc2[mf][nf][rg] + bk1[n] - bk2[n]);
                }
    } else {
        // ---- vt (transposed V projection)
        int id2 = id - 128;
        int bx = id2 & 7, by = (id2 >> 3) & 1, z = id2 >> 4;
        int b = z >> 1, which = z & 1;
        const u16* A = which ? wv2b : wv1b;
        const u16* Bt = (which ? y2b : y1b) + (size_t)b * K_ * C_;
        const float* bias = which ? bv2 : bv1;
        u16* outp = (which ? vt2 : vt1) + (size_t)b * C_ * K_;
        int m0 = bx * 64, n0 = by * 64;
        floatx4 acc[4][4] = {};
        for (int ch = 0; ch < 16; ++ch) {
            int koff = ch * 32 + (l >> 4) * 8;
            short8v a[4], wv[4];
#pragma unroll
            for (int mf = 0; mf < 4; ++mf) a[mf] = *(const short8v*)(A + (size_t)(m0 + mf*16 + (l & 15)) * 512 + koff);
#pragma unroll
            for (int nf = 0; nf < 4; ++nf) wv[nf] = *(const short8v*)(Bt + (size_t)(n0 + nf*16 + (l & 15)) * 512 + koff);
#pragma unroll
            for (int mf = 0; mf < 4; ++mf)
#pragma unroll
                for (int nf = 0; nf < 4; ++nf)
                    acc[mf][nf] = __builtin_amdgcn_mfma_f32_16x16x32_bf16(a[mf], wv[nf], acc[mf][nf], 0, 0, 0);
        }
#pragma unroll
        for (int mf = 0; mf < 4; ++mf)
#pragma unroll
            for (int nf = 0; nf < 4; ++nf)
#pragma unroll
                for (int rg = 0; rg < 4; ++rg) {
                    int m = m0 + mf*16 + (l >> 4)*4 + rg;
                    int n = n0 + nf*16 + (l & 15);
                    outp[(size_t)m * 128 + n] = f2bf(acc[mf][nf][rg] + bias[m]);
                }
    }
}

// ---------------------------------------------------------------------------
// P2b: ebd[b*128+key] = bq_cat . kd_row
// ---------------------------------------------------------------------------
__global__ void ebd_k(const u16* __restrict__ kd,
                      const float* __restrict__ bq1, const float* __restrict__ bq2,
                      float* ebd) {
    int tid = blockIdx.x * 256 + threadIdx.x;  // 2048
    const u16* kb = kd + (size_t)tid * 256;
    float s = 0.f;
    for (int d = 0; d < 128; ++d) s += bq1[d] * bf2f(kb[d]);
    for (int d = 0; d < 128; ++d) s += bq2[d] * bf2f(kb[128 + d]);
    ebd[tid] = s;
}

// ---------------------------------------------------------------------------
// P3: kkd1/kkd2 [b][key][512] bf16 = kd_half @ wqt^T (K=128 over d)
// ---------------------------------------------------------------------------
__global__ void gemm_gkk(const u16* __restrict__ kd,
                         const u16* __restrict__ wq1t, const u16* __restrict__ wq2t,
                         u16* kkd1, u16* kkd2) {
    int l = threadIdx.x;
    int z = blockIdx.z; int b = z >> 1; int which = z & 1;
    const u16* A = kd + (size_t)b * K_ * 256 + which * 128;
    const u16* Wt = which ? wq2t : wq1t;
    u16* outp = (which ? kkd2 : kkd1) + (size_t)b * K_ * C_;
    int m0 = blockIdx.x * 64, n0 = blockIdx.y * 64;
    floatx4 acc[4][4] = {};
    for (int ch = 0; ch < 4; ++ch) {
        int koff = ch * 32 + (l >> 4) * 8;
        short8v a[4], wv[4];
#pragma unroll
        for (int mf = 0; mf < 4; ++mf) a[mf] = *(const short8v*)(A + (size_t)(m0 + mf*16 + (l & 15)) * 256 + koff);
#pragma unroll
        for (int nf = 0; nf < 4; ++nf) wv[nf] = *(const short8v*)(Wt + (size_t)(n0 + nf*16 + (l & 15)) * 128 + koff);
#pragma unroll
        for (int mf = 0; mf < 4; ++mf)
#pragma unroll
            for (int nf = 0; nf < 4; ++nf)
                acc[mf][nf] = __builtin_amdgcn_mfma_f32_16x16x32_bf16(a[mf], wv[nf], acc[mf][nf], 0, 0, 0);
    }
#pragma unroll
    for (int mf = 0; mf < 4; ++mf)
#pragma unroll
        for (int nf = 0; nf < 4; ++nf)
#pragma unroll
            for (int rg = 0; rg < 4; ++rg) {
                int m = m0 + mf*16 + (l >> 4)*4 + rg;
                int n = n0 + nf*16 + (l & 15);
                outp[(size_t)m * C_ + n] = f2bf(acc[mf][nf][rg]);
            }
}

// ---------------------------------------------------------------------------
// E kernel: ediff = x_cat . kkd_cat (K=1024) + ebd, softmax(|.|) fused, attn out.
// grid 512 (32 px-tiles x 16 b), block 256 (4 waves). Tile 128 px x 128 keys.
// x and kk LDS-staged (dbuf 64 KB), 1 barrier/step, 16 steps.  [UNCHANGED]
// ---------------------------------------------------------------------------
__global__ __launch_bounds__(256, 2)
void e_attn(const float* __restrict__ x1, const float* __restrict__ x2,
            const u16* __restrict__ kkd1, const u16* __restrict__ kkd2,
            const float* __restrict__ ebd, u16* __restrict__ attnb) {
    __shared__ u16 xT[2][128 * 64];    // 2x16 KB  [px][ch] bf16 swizzled
    __shared__ u16 kkS[2][128 * 64];   // 2x16 KB  [key][ch] bf16 swizzled

    int id = blockIdx.x;
    int sw = ((id & 7) << 6) | (id >> 3);   // XCD swizzle, 512 = 8*64 bijective
    int b = sw >> 5;
    int n0 = (sw & 31) * 128;
    int t = threadIdx.x, w = t >> 6, l = t & 63;

    const float* xs[2] = { x1 + (size_t)b * C_ * N_, x2 + (size_t)b * C_ * N_ };
    const u16* kkp[2] = { kkd1 + (size_t)b * K_ * C_, kkd2 + (size_t)b * K_ * C_ };

    floatx4 ed[2][8] = {};   // wave: px rows w*32+mf*16.., all 128 keys

    float xA0[16], xA1[16], xB0[16], xB1[16];
    short8v kvA[4], kvB[4];

    auto SLOAD = [&](int s, float (&v0)[16], float (&v1)[16], short8v (&kv)[4]) {
        int h = s >> 3, c0 = (s & 7) * 64;
        const float* xp = xs[h] + (size_t)(c0 + w * 16) * N_ + n0 + 2 * l;
#pragma unroll
        for (int j = 0; j < 16; ++j) {
            float2 f = *(const float2*)(xp + (size_t)j * N_);
            v0[j] = f.x; v1[j] = f.y;
        }
        const u16* kp = kkp[h] + c0;
#pragma unroll
        for (int i = 0; i < 4; ++i) {
            int gi = i * 256 + t;
            kv[i] = *(const short8v*)(kp + (size_t)(gi >> 3) * 512 + (gi & 7) * 8);
        }
    };
    auto SWRITE = [&](int buf, float (&v0)[16], float (&v1)[16], short8v (&kv)[4]) {
        short8v p00, p01, p10, p11;
#pragma unroll
        for (int j = 0; j < 8; ++j) {
            p00[j] = (short)f2bf(v0[j]);  p01[j] = (short)f2bf(v0[j + 8]);
            p10[j] = (short)f2bf(v1[j]);  p11[j] = (short)f2bf(v1[j + 8]);
        }
        u16* xb = xT[buf];
        int row0 = 2 * l, sz = l & 7;
        *(short8v*)&xb[row0 * 64 + 8 * ((w * 2) ^ sz)] = p00;
        *(short8v*)&xb[row0 * 64 + 8 * ((w * 2 + 1) ^ sz)] = p01;
        *(short8v*)&xb[(row0 + 1) * 64 + 8 * ((w * 2) ^ sz)] = p10;
        *(short8v*)&xb[(row0 + 1) * 64 + 8 * ((w * 2 + 1) ^ sz)] = p11;
        u16* kb = kkS[buf];
#pragma unroll
        for (int i = 0; i < 4; ++i) {
            int gi = i * 256 + t;
            int key = gi >> 3, g = gi & 7;
            *(short8v*)&kb[key * 64 + 8 * (g ^ (key & 7))] = kv[i];
        }
    };
    auto COMPUTE = [&](int buf) {
        u16* xb = xT[buf]; u16* kb = kkS[buf];
#pragma unroll
        for (int cc = 0; cc < 2; ++cc) {
            short8v a[2];
#pragma unroll
            for (int mf = 0; mf < 2; ++mf) {
                int row = w * 32 + mf * 16 + (l & 15);
                int g = cc * 4 + (l >> 4);
                a[mf] = *(const short8v*)&xb[row * 64 + 8 * (g ^ ((row >> 1) & 7))];
            }
#pragma unroll
            for (int kf = 0; kf < 8; ++kf) {
                int key = kf * 16 + (l & 15);
                int g = cc * 4 + (l >> 4);
                short8v bb = *(const short8v*)&kb[key * 64 + 8 * (g ^ (key & 7))];
#pragma unroll
                for (int mf = 0; mf < 2; ++mf)
                    ed[mf][kf] = __builtin_amdgcn_mfma_f32_16x16x32_bf16(a[mf], bb, ed[mf][kf], 0, 0, 0);
            }
        }
    };

    // ---- K-loop: 16 steps of 64 ch, double-buffered, 1 barrier/step
    SLOAD(0, xA0, xA1, kvA);
    SWRITE(0, xA0, xA1, kvA);
    SLOAD(1, xB0, xB1, kvB);
#pragma unroll
    for (int rr = 0; rr < 8; ++rr) {
        int sA = 2 * rr, sB = 2 * rr + 1;
        __syncthreads();
        COMPUTE(0);
        SWRITE(1, xB0, xB1, kvB);
        if (sA + 2 <= 15) SLOAD(sA + 2, xA0, xA1, kvA);
        __syncthreads();
        COMPUTE(1);
        if (sB + 1 <= 15) SWRITE(0, xA0, xA1, kvA);
        if (sB + 2 <= 15) SLOAD(sB + 2, xB0, xB1, kvB);
    }

    // ---- fused softmax over 128 keys of |ediff + ebd| (in-register)
    float ebv[8];
#pragma unroll
    for (int kf = 0; kf < 8; ++kf) ebv[kf] = ebd[b * 128 + kf * 16 + (l & 15)];
#pragma unroll
    for (int mf = 0; mf < 2; ++mf)
#pragma unroll
        for (int kf = 0; kf < 8; ++kf)
#pragma unroll
            for (int rg = 0; rg < 4; ++rg)
                ed[mf][kf][rg] = fabsf(ed[mf][kf][rg] + ebv[kf]);

    float mx[2][4], sm[2][4];
#pragma unroll
    for (int mf = 0; mf < 2; ++mf)
#pragma unroll
        for (int rg = 0; rg < 4; ++rg) {
            float m = fmaxf(ed[mf][0][rg], ed[mf][1][rg]);
            m = fmaxf(m, fmaxf(ed[mf][2][rg], ed[mf][3][rg]));
            m = fmaxf(m, fmaxf(ed[mf][4][rg], ed[mf][5][rg]));
            m = fmaxf(m, fmaxf(ed[mf][6][rg], ed[mf][7][rg]));
            mx[mf][rg] = m;
        }
#pragma unroll
    for (int st = 1; st < 16; st <<= 1)
#pragma unroll
        for (int mf = 0; mf < 2; ++mf)
#pragma unroll
            for (int rg = 0; rg < 4; ++rg)
                mx[mf][rg] = fmaxf(mx[mf][rg], __shfl_xor(mx[mf][rg], st));
#pragma unroll
    for (int mf = 0; mf < 2; ++mf)
#pragma unroll
        for (int rg = 0; rg < 4; ++rg) sm[mf][rg] = 0.f;
#pragma unroll
    for (int mf = 0; mf < 2; ++mf)
#pragma unroll
        for (int kf = 0; kf < 8; ++kf)
#pragma unroll
            for (int rg = 0; rg < 4; ++rg) {
                float e = __expf(ed[mf][kf][rg] - mx[mf][rg]);
                ed[mf][kf][rg] = e;
                sm[mf][rg] += e;
            }
#pragma unroll
    for (int st = 1; st < 16; st <<= 1)
#pragma unroll
        for (int mf = 0; mf < 2; ++mf)
#pragma unroll
            for (int rg = 0; rg < 4; ++rg)
                sm[mf][rg] += __shfl_xor(sm[mf][rg], st);
#pragma unroll
    for (int mf = 0; mf < 2; ++mf)
#pragma unroll
        for (int rg = 0; rg < 4; ++rg) sm[mf][rg] = 1.0f / sm[mf][rg];

    // ---- write attn bf16 [b][px][128k]
    u16* ap = attnb + ((size_t)(b * N_ + n0)) * 128;
#pragma unroll
    for (int mf = 0; mf < 2; ++mf)
#pragma unroll
        for (int rg = 0; rg < 4; ++rg) {
            int row = w * 32 + mf * 16 + (l >> 4) * 4 + rg;
#pragma unroll
            for (int kf = 0; kf < 8; ++kf) {
                int col = kf * 16 + (l & 15);
                ap[(size_t)row * 128 + col] = f2bf(ed[mf][kf][rg] * sm[mf][rg]);
            }
        }
}

// ---------------------------------------------------------------------------
// PV kernel: O[c][n] = vt[c][k].attn[n][k]; out = sc*O + x. K=128, no K-loop.
// grid 4096 (32 px x 8 c x 16 b), block 256 (4 waves), tile 128c x 128px.
// mf-halves sequential (low VGPR) -> 4 blocks/CU. ONE barrier. Residual streamed.
// ---------------------------------------------------------------------------
__global__ __launch_bounds__(256, 4)
void pv_attn(const float* __restrict__ x1, const float* __restrict__ x2,
             const u16* __restrict__ vt1, const u16* __restrict__ vt2,
             const u16* __restrict__ attnb, const float* __restrict__ scale_p,
             float* __restrict__ out1, float* __restrict__ out2) {
    __shared__ u16 As[128 * 128];   // 32 KB, [px][k] bf16 swizzled (16 granules/row)

    int id = blockIdx.x;
    int sw = ((id & 7) << 9) | (id >> 3);   // XCD swizzle, 4096 = 8*512 bijective
    int b = sw >> 8;
    int ct = (sw >> 5) & 7;
    int pt = sw & 31;
    int n0 = pt * 128;
    int cb = ct * 128;
    int oi = cb >> 9;          // 0: out1/vt1/x1, 1: out2/vt2/x2
    int cbl = cb & 511;
    int t = threadIdx.x, w = t >> 6, l = t & 63;

    const float sc = scale_p[0];
    const u16* vt = (oi ? vt2 : vt1) + (size_t)b * C_ * K_;
    const float* xr = (oi ? x2 : x1) + (size_t)b * C_ * N_;
    float* op = (oi ? out2 : out1) + (size_t)b * C_ * N_;

    // stage attn tile (rows n0..n0+127, fully linear 32 KB) -> LDS swizzled
    const u16* ap = attnb + ((size_t)(b * N_ + n0)) * 128;
#pragma unroll
    for (int p = 0; p < 8; ++p) {
        int gi = p * 256 + t;
        int px = gi >> 4, g = gi & 15;
        short8v v = *(const short8v*)(ap + (size_t)gi * 8);
        *(short8v*)&As[px * 128 + 8 * (g ^ (px & 15))] = v;
    }
    __syncthreads();   // the only barrier

#pragma unroll
    for (int mf = 0; mf < 2; ++mf) {
        short8v vf[4];
#pragma unroll
        for (int kc = 0; kc < 4; ++kc)
            vf[kc] = *(const short8v*)(vt + (size_t)(cbl + w * 32 + mf * 16 + (l & 15)) * K_ + kc * 32 + (l >> 4) * 8);
        floatx4 o[8] = {};
#pragma unroll
        for (int kc = 0; kc < 4; ++kc) {
#pragma unroll
            for (int nf = 0; nf < 8; ++nf) {
                int row = nf * 16 + (l & 15);
                int g = kc * 4 + (l >> 4);
                short8v bb = *(const short8v*)&As[row * 128 + 8 * (g ^ (row & 15))];
                o[nf] = __builtin_amdgcn_mfma_f32_16x16x32_bf16(vf[kc], bb, o[nf], 0, 0, 0);
            }
        }
#pragma unroll
        for (int rg = 0; rg < 4; ++rg) {
            size_t rowoff = (size_t)(cbl + w * 32 + mf * 16 + (l >> 4) * 4 + rg) * N_ + n0 + (l & 15);
#pragma unroll
            for (int nf = 0; nf < 8; ++nf)
                op[rowoff + nf * 16] = sc * o[nf][rg] + xr[rowoff + nf * 16];
        }
    }
}

// ---------------------------------------------------------------------------
extern "C" void kernel_launch(void* const* d_in, const int* in_sizes, int n_in,
                              void* d_out, int out_size, void* d_ws, size_t ws_size,
                              hipStream_t stream) {
    const float* x1 = (const float*)d_in[0];
    const float* y1 = (const float*)d_in[1];
    const float* x2 = (const float*)d_in[2];
    const float* y2 = (const float*)d_in[3];
    const float* wq1 = (const float*)d_in[4];
    const float* bq1 = (const float*)d_in[5];
    const float* wq2 = (const float*)d_in[6];
    const float* bq2 = (const float*)d_in[7];
    const float* wk1 = (const float*)d_in[8];
    const float* bk1 = (const float*)d_in[9];
    const float* wk2 = (const float*)d_in[10];
    const float* bk2 = (const float*)d_in[11];
    const float* wv1 = (const float*)d_in[12];
    const float* bv1 = (const float*)d_in[13];
    const float* wv2 = (const float*)d_in[14];
    const float* bv2 = (const float*)d_in[15];
    const float* scale = (const float*)d_in[16];

    char* ws = (char*)d_ws;
    u16* y1b  = (u16*)(ws + 0);
    u16* y2b  = (u16*)(ws + 2097152);
    u16* wk1b = (u16*)(ws + 4194304);
    u16* wk2b = (u16*)(ws + 4456448);
    u16* wv1b = (u16*)(ws + 4718592);
    u16* wv2b = (u16*)(ws + 5242880);
    u16* wq1t = (u16*)(ws + 5767168);
    u16* wq2t = (u16*)(ws + 5898240);
    u16* kd   = (u16*)(ws + 8126464);
    u16* kkd1 = (u16*)(ws + 9175040);
    u16* kkd2 = (u16*)(ws + 11272192);
    u16* vt1  = (u16*)(ws + 13369344);
    u16* vt2  = (u16*)(ws + 15466496);
    float* ebd = (float*)(ws + 17563648);
    u16* attnb = (u16*)(ws + 17571840);   // 16 MB

    float* out1 = (float*)d_out;
    float* out2 = out1 + (size_t)B_ * C_ * N_;

    hipLaunchKernelGGL(conv_all, dim3(11776), dim3(256), 0, stream,
                       y1, y2, wk1, wk2, wv1, wv2, wq1, wq2,
                       y1b, y2b, wk1b, wk2b, wv1b, wv2b, wq1t, wq2t);
    hipLaunchKernelGGL(gemm_gkdgv, dim3(640), dim3(64), 0, stream,
                       y1b, y2b, wk1b, wk2b, wv1b, wv2b, bk1, bk2, bv1, bv2,
                       kd, vt1, vt2);
    hipLaunchKernelGGL(ebd_k, dim3(8), dim3(256), 0, stream, kd, bq1, bq2, ebd);
    hipLaunchKernelGGL(gemm_gkk, dim3(2, 8, 32), dim3(64), 0, stream,
                       kd, wq1t, wq2t, kkd1, kkd2);
    hipLaunchKernelGGL(e_attn, dim3(512), dim3(256), 0, stream,
                       x1, x2, kkd1, kkd2, ebd, attnb);
    hipLaunchKernelGGL(pv_attn, dim3(4096), dim3(256), 0, stream,
                       x1, x2, vt1, vt2, attnb, scale, out1, out2);
}

// Round 9
// 232.203 us; speedup vs baseline: 1.3160x; 1.3160x over previous
//
#include <hip/hip_runtime.h>

typedef unsigned short u16;
typedef __attribute__((ext_vector_type(8))) short short8v;
typedef __attribute__((ext_vector_type(4))) float floatx4;

#define B_ 16
#define C_ 512
#define N_ 4096
#define K_ 128   // keys

__device__ __forceinline__ float bf2f(u16 u) {
    unsigned int x = ((unsigned int)u) << 16;
    return __builtin_bit_cast(float, x);
}
__device__ __forceinline__ u16 f2bf(float f) {
    unsigned int u = __builtin_bit_cast(unsigned int, f);
    u = u + 0x7FFFu + ((u >> 16) & 1u);
    return (u16)(u >> 16);
}
// async global(16B) -> LDS, wave-uniform dest base + lane*16
__device__ __forceinline__ void gload_lds16(const u16* g, u16* l) {
    __builtin_amdgcn_global_load_lds(
        (const __attribute__((address_space(1))) void*)g,
        (__attribute__((address_space(3))) void*)l, 16, 0, 0);
}

// ---------------------------------------------------------------------------
// P0: fp32 -> bf16 converts (y1,y2,wk1,wk2,wv1,wv2) + wq transpose, one launch
// ---------------------------------------------------------------------------
__global__ void conv_all(const float* __restrict__ y1, const float* __restrict__ y2,
                         const float* __restrict__ wk1, const float* __restrict__ wk2,
                         const float* __restrict__ wv1, const float* __restrict__ wv2,
                         const float* __restrict__ wq1, const float* __restrict__ wq2,
                         u16* y1b, u16* y2b, u16* wk1b, u16* wk2b, u16* wv1b, u16* wv2b,
                         u16* wq1t, u16* wq2t) {
    int tid = blockIdx.x * 256 + threadIdx.x;
    const int SY = B_ * K_ * C_;        // 1048576
    const int SWK = 256 * 512;          // 131072
    const int SWV = 512 * 512;          // 262144
    const int SQ = 128 * 512;           // 65536
    int base = 2*SY + 2*SWK + 2*SWV;
    if (tid < base) {
        const float* src; u16* dst; int off;
        if (tid < SY)                 { src = y1;  dst = y1b;  off = tid; }
        else if (tid < 2*SY)          { src = y2;  dst = y2b;  off = tid - SY; }
        else if (tid < 2*SY+SWK)      { src = wk1; dst = wk1b; off = tid - 2*SY; }
        else if (tid < 2*SY+2*SWK)    { src = wk2; dst = wk2b; off = tid - 2*SY - SWK; }
        else if (tid < 2*SY+2*SWK+SWV){ src = wv1; dst = wv1b; off = tid - 2*SY - 2*SWK; }
        else                          { src = wv2; dst = wv2b; off = tid - 2*SY - 2*SWK - SWV; }
        dst[off] = f2bf(src[off]);
    } else {
        int e = tid - base;           // 0 .. 2*SQ-1
        const float* s = (e >= SQ) ? wq2 : wq1;
        u16* d = (e >= SQ) ? wq2t : wq1t;
        e &= (SQ - 1);
        int dd = e >> 9;              // 0..127
        int c = e & 511;              // coalesced read over c
        d[c * 128 + dd] = f2bf(s[dd * 512 + c]);
    }
}

// ---------------------------------------------------------------------------
// P1: k1b/k2b [b][key][256] = y @ wk^T + bk  AND  vt1/vt2 [b][c][128] = (y@wv^T+bv)^T
// ---------------------------------------------------------------------------
__global__ void gemm_gkgv(const u16* __restrict__ y1b, const u16* __restrict__ y2b,
                          const u16* __restrict__ wk1b, const u16* __restrict__ wk2b,
                          const u16* __restrict__ wv1b, const u16* __restrict__ wv2b,
                          const float* __restrict__ bk1, const float* __restrict__ bk2,
                          const float* __restrict__ bv1, const float* __restrict__ bv2,
                          u16* k1b, u16* k2b, u16* vt1, u16* vt2) {
    int l = threadIdx.x;
    int id = blockIdx.x;
    const u16 *A, *Bt; const float* bias; u16* outp;
    int m0, n0, po; bool bias_m;
    if (id < 256) {
        int bx = id & 1, by = (id >> 1) & 3, z = id >> 3;
        int b = z >> 1, which = z & 1;
        A = (which ? y2b : y1b) + (size_t)b * K_ * C_;
        Bt = which ? wk2b : wk1b;
        bias = which ? bk2 : bk1;
        outp = (which ? k2b : k1b) + (size_t)b * K_ * 256;
        m0 = bx * 64; n0 = by * 64; po = 256; bias_m = false;
    } else {
        int id2 = id - 256;
        int bx = id2 & 7, by = (id2 >> 3) & 1, z = id2 >> 4;
        int b = z >> 1, which = z & 1;
        A = which ? wv2b : wv1b;
        Bt = (which ? y2b : y1b) + (size_t)b * K_ * C_;
        bias = which ? bv2 : bv1;
        outp = (which ? vt2 : vt1) + (size_t)b * C_ * K_;
        m0 = bx * 64; n0 = by * 64; po = 128; bias_m = true;
    }
    floatx4 acc[4][4] = {};
    for (int ch = 0; ch < 16; ++ch) {
        int koff = ch * 32 + (l >> 4) * 8;
        short8v a[4], wv[4];
#pragma unroll
        for (int mf = 0; mf < 4; ++mf) a[mf] = *(const short8v*)(A + (size_t)(m0 + mf*16 + (l & 15)) * 512 + koff);
#pragma unroll
        for (int nf = 0; nf < 4; ++nf) wv[nf] = *(const short8v*)(Bt + (size_t)(n0 + nf*16 + (l & 15)) * 512 + koff);
#pragma unroll
        for (int mf = 0; mf < 4; ++mf)
#pragma unroll
            for (int nf = 0; nf < 4; ++nf)
                acc[mf][nf] = __builtin_amdgcn_mfma_f32_16x16x32_bf16(a[mf], wv[nf], acc[mf][nf], 0, 0, 0);
    }
#pragma unroll
    for (int mf = 0; mf < 4; ++mf)
#pragma unroll
        for (int nf = 0; nf < 4; ++nf)
#pragma unroll
            for (int rg = 0; rg < 4; ++rg) {
                int m = m0 + mf*16 + (l >> 4)*4 + rg;
                int n = n0 + nf*16 + (l & 15);
                outp[(size_t)m * po + n] = f2bf(acc[mf][nf][rg] + (bias_m ? bias[m] : bias[n]));
            }
}

// ---------------------------------------------------------------------------
// P2: kd = k1b - k2b (bf16); P2b: ebd = bq_cat . kd_row
// ---------------------------------------------------------------------------
__global__ void kd_sub(const u16* __restrict__ k1b, const u16* __restrict__ k2b,
                       u16* kd) {
    int tid = blockIdx.x * 256 + threadIdx.x;
    kd[tid] = f2bf(bf2f(k1b[tid]) - bf2f(k2b[tid]));
}

__global__ void ebd_k(const u16* __restrict__ kd,
                      const float* __restrict__ bq1, const float* __restrict__ bq2,
                      float* ebd) {
    int tid = blockIdx.x * 256 + threadIdx.x;  // 2048
    const u16* kb = kd + (size_t)tid * 256;
    float s = 0.f;
    for (int d = 0; d < 128; ++d) s += bq1[d] * bf2f(kb[d]);
    for (int d = 0; d < 128; ++d) s += bq2[d] * bf2f(kb[128 + d]);
    ebd[tid] = s;
}

// ---------------------------------------------------------------------------
// P3: kkd1/kkd2 [b][key][512] bf16 = kd_half @ wqt^T (K=128 over d)
// ---------------------------------------------------------------------------
__global__ void gemm_gkk(const u16* __restrict__ kd,
                         const u16* __restrict__ wq1t, const u16* __restrict__ wq2t,
                         u16* kkd1, u16* kkd2) {
    int l = threadIdx.x;
    int z = blockIdx.z; int b = z >> 1; int which = z & 1;
    const u16* A = kd + (size_t)b * K_ * 256 + which * 128;
    const u16* Wt = which ? wq2t : wq1t;
    u16* outp = (which ? kkd2 : kkd1) + (size_t)b * K_ * C_;
    int m0 = blockIdx.x * 64, n0 = blockIdx.y * 64;
    floatx4 acc[4][4] = {};
    for (int ch = 0; ch < 4; ++ch) {
        int koff = ch * 32 + (l >> 4) * 8;
        short8v a[4], wv[4];
#pragma unroll
        for (int mf = 0; mf < 4; ++mf) a[mf] = *(const short8v*)(A + (size_t)(m0 + mf*16 + (l & 15)) * 256 + koff);
#pragma unroll
        for (int nf = 0; nf < 4; ++nf) wv[nf] = *(const short8v*)(Wt + (size_t)(n0 + nf*16 + (l & 15)) * 128 + koff);
#pragma unroll
        for (int mf = 0; mf < 4; ++mf)
#pragma unroll
            for (int nf = 0; nf < 4; ++nf)
                acc[mf][nf] = __builtin_amdgcn_mfma_f32_16x16x32_bf16(a[mf], wv[nf], acc[mf][nf], 0, 0, 0);
    }
#pragma unroll
    for (int mf = 0; mf < 4; ++mf)
#pragma unroll
        for (int nf = 0; nf < 4; ++nf)
#pragma unroll
            for (int rg = 0; rg < 4; ++rg) {
                int m = m0 + mf*16 + (l >> 4)*4 + rg;
                int n = n0 + nf*16 + (l & 15);
                outp[(size_t)m * C_ + n] = f2bf(acc[mf][nf][rg]);
            }
}

// ---------------------------------------------------------------------------
// E kernel: ediff = x_cat . kkd_cat (K=1024) + ebd, softmax(|.|) fused, attn out.
// grid 512, block 256 (4 waves). Tile 128 px x 128 keys. x reg-staged -> LDS;
// kk staged via global_load_lds(16B) with PRE-SWIZZLED SOURCE (linear LDS dest,
// swizzle applied on read — rule #21). 1 barrier/step, 16 steps.
// ---------------------------------------------------------------------------
__global__ __launch_bounds__(256, 2)
void e_attn(const float* __restrict__ x1, const float* __restrict__ x2,
            const u16* __restrict__ kkd1, const u16* __restrict__ kkd2,
            const float* __restrict__ ebd, u16* __restrict__ attnb) {
    __shared__ u16 xT[2][128 * 64];    // 2x16 KB  [px][ch] bf16 swizzled
    __shared__ u16 kkS[2][128 * 64];   // 2x16 KB  [key][ch] bf16 (content pre-swizzled)

    int id = blockIdx.x;
    int sw = ((id & 7) << 6) | (id >> 3);   // XCD swizzle, 512 = 8*64 bijective
    int b = sw >> 5;
    int n0 = (sw & 31) * 128;
    int t = threadIdx.x, w = t >> 6, l = t & 63;

    const float* xs[2] = { x1 + (size_t)b * C_ * N_, x2 + (size_t)b * C_ * N_ };
    const u16* kkp[2] = { kkd1 + (size_t)b * K_ * C_, kkd2 + (size_t)b * K_ * C_ };

    floatx4 ed[2][8] = {};   // wave: px rows w*32+mf*16.., all 128 keys

    float xA0[16], xA1[16], xB0[16], xB1[16];

    auto SLOADX = [&](int s, float (&v0)[16], float (&v1)[16]) {
        int h = s >> 3, c0 = (s & 7) * 64;
        const float* xp = xs[h] + (size_t)(c0 + w * 16) * N_ + n0 + 2 * l;
#pragma unroll
        for (int j = 0; j < 16; ++j) {
            float2 f = *(const float2*)(xp + (size_t)j * N_);
            v0[j] = f.x; v1[j] = f.y;
        }
    };
    // async kk stage: granule gi = i*256+t; key = gi>>3, phys granule gp = gi&7;
    // source granule = gp ^ (key&7)  =>  read at 8*(g^(key&7)) returns granule g.
    auto KLDS = [&](int s, int buf) {
        int h = s >> 3, c0 = (s & 7) * 64;
        const u16* kp = kkp[h] + c0;
#pragma unroll
        for (int i = 0; i < 4; ++i) {
            int gi = i * 256 + t;
            int key = gi >> 3, gp = gi & 7;
            gload_lds16(kp + (size_t)key * 512 + (gp ^ (key & 7)) * 8,
                        &kkS[buf][(i * 256 + w * 64) * 8]);
        }
    };
    auto SWRITEX = [&](int buf, float (&v0)[16], float (&v1)[16]) {
        short8v p00, p01, p10, p11;
#pragma unroll
        for (int j = 0; j < 8; ++j) {
            p00[j] = (short)f2bf(v0[j]);  p01[j] = (short)f2bf(v0[j + 8]);
            p10[j] = (short)f2bf(v1[j]);  p11[j] = (short)f2bf(v1[j + 8]);
        }
        u16* xb = xT[buf];
        int row0 = 2 * l, sz = l & 7;
        *(short8v*)&xb[row0 * 64 + 8 * ((w * 2) ^ sz)] = p00;
        *(short8v*)&xb[row0 * 64 + 8 * ((w * 2 + 1) ^ sz)] = p01;
        *(short8v*)&xb[(row0 + 1) * 64 + 8 * ((w * 2) ^ sz)] = p10;
        *(short8v*)&xb[(row0 + 1) * 64 + 8 * ((w * 2 + 1) ^ sz)] = p11;
    };
    auto COMPUTE = [&](int buf) {
        u16* xb = xT[buf]; u16* kb = kkS[buf];
#pragma unroll
        for (int cc = 0; cc < 2; ++cc) {
            short8v a[2];
#pragma unroll
            for (int mf = 0; mf < 2; ++mf) {
                int row = w * 32 + mf * 16 + (l & 15);
                int g = cc * 4 + (l >> 4);
                a[mf] = *(const short8v*)&xb[row * 64 + 8 * (g ^ ((row >> 1) & 7))];
            }
#pragma unroll
            for (int kf = 0; kf < 8; ++kf) {
                int key = kf * 16 + (l & 15);
                int g = cc * 4 + (l >> 4);
                short8v bb = *(const short8v*)&kb[key * 64 + 8 * (g ^ (key & 7))];
#pragma unroll
                for (int mf = 0; mf < 2; ++mf)
                    ed[mf][kf] = __builtin_amdgcn_mfma_f32_16x16x32_bf16(a[mf], bb, ed[mf][kf], 0, 0, 0);
            }
        }
    };

    // ---- K-loop: 16 steps of 64 ch, double-buffered, 1 barrier/step
    SLOADX(0, xA0, xA1); KLDS(0, 0);
    SWRITEX(0, xA0, xA1);
    SLOADX(1, xB0, xB1); KLDS(1, 1);
#pragma unroll
    for (int rr = 0; rr < 8; ++rr) {
        int sA = 2 * rr, sB = 2 * rr + 1;
        __syncthreads();                       // drains gload_lds + ds_writes
        if (rr > 0) KLDS(sB, 1);               // kk for sB (buf1 free: last read pre-barrier)
        COMPUTE(0);
        SWRITEX(1, xB0, xB1);                  // x for sB
        if (sA + 2 <= 15) SLOADX(sA + 2, xA0, xA1);
        __syncthreads();
        if (sA + 2 <= 15) KLDS(sA + 2, 0);     // kk for sA+2 into buf0
        COMPUTE(1);
        if (sB + 1 <= 15) SWRITEX(0, xA0, xA1);
        if (sB + 2 <= 15) SLOADX(sB + 2, xB0, xB1);
    }

    // ---- fused softmax over 128 keys of |ediff + ebd| (in-register)
    float ebv[8];
#pragma unroll
    for (int kf = 0; kf < 8; ++kf) ebv[kf] = ebd[b * 128 + kf * 16 + (l & 15)];
#pragma unroll
    for (int mf = 0; mf < 2; ++mf)
#pragma unroll
        for (int kf = 0; kf < 8; ++kf)
#pragma unroll
            for (int rg = 0; rg < 4; ++rg)
                ed[mf][kf][rg] = fabsf(ed[mf][kf][rg] + ebv[kf]);

    float mx[2][4], sm[2][4];
#pragma unroll
    for (int mf = 0; mf < 2; ++mf)
#pragma unroll
        for (int rg = 0; rg < 4; ++rg) {
            float m = fmaxf(ed[mf][0][rg], ed[mf][1][rg]);
            m = fmaxf(m, fmaxf(ed[mf][2][rg], ed[mf][3][rg]));
            m = fmaxf(m, fmaxf(ed[mf][4][rg], ed[mf][5][rg]));
            m = fmaxf(m, fmaxf(ed[mf][6][rg], ed[mf][7][rg]));
            mx[mf][rg] = m;
        }
#pragma unroll
    for (int st = 1; st < 16; st <<= 1)
#pragma unroll
        for (int mf = 0; mf < 2; ++mf)
#pragma unroll
            for (int rg = 0; rg < 4; ++rg)
                mx[mf][rg] = fmaxf(mx[mf][rg], __shfl_xor(mx[mf][rg], st));
#pragma unroll
    for (int mf = 0; mf < 2; ++mf)
#pragma unroll
        for (int rg = 0; rg < 4; ++rg) sm[mf][rg] = 0.f;
#pragma unroll
    for (int mf = 0; mf < 2; ++mf)
#pragma unroll
        for (int kf = 0; kf < 8; ++kf)
#pragma unroll
            for (int rg = 0; rg < 4; ++rg) {
                float e = __expf(ed[mf][kf][rg] - mx[mf][rg]);
                ed[mf][kf][rg] = e;
                sm[mf][rg] += e;
            }
#pragma unroll
    for (int st = 1; st < 16; st <<= 1)
#pragma unroll
        for (int mf = 0; mf < 2; ++mf)
#pragma unroll
            for (int rg = 0; rg < 4; ++rg)
                sm[mf][rg] += __shfl_xor(sm[mf][rg], st);
#pragma unroll
    for (int mf = 0; mf < 2; ++mf)
#pragma unroll
        for (int rg = 0; rg < 4; ++rg) sm[mf][rg] = 1.0f / sm[mf][rg];

    // ---- write attn bf16 [b][px][128k]
    u16* ap = attnb + ((size_t)(b * N_ + n0)) * 128;
#pragma unroll
    for (int mf = 0; mf < 2; ++mf)
#pragma unroll
        for (int rg = 0; rg < 4; ++rg) {
            int row = w * 32 + mf * 16 + (l >> 4) * 4 + rg;
#pragma unroll
            for (int kf = 0; kf < 8; ++kf) {
                int col = kf * 16 + (l & 15);
                ap[(size_t)row * 128 + col] = f2bf(ed[mf][kf][rg] * sm[mf][rg]);
            }
        }
}

// ---------------------------------------------------------------------------
// PV kernel: O[c][n] = vt[c][k].attn[n][k]; out = sc*O + x. K=128, no K-loop.
// grid 4096, block 256 (4 waves), tile 128c x 128px. attn staged async via
// global_load_lds (pre-swizzled source); vf/rs loads pre-barrier (R7 placement).
// ---------------------------------------------------------------------------
__global__ __launch_bounds__(256, 2)
void pv_attn(const float* __restrict__ x1, const float* __restrict__ x2,
             const u16* __restrict__ vt1, const u16* __restrict__ vt2,
             const u16* __restrict__ attnb, const float* __restrict__ scale_p,
             float* __restrict__ out1, float* __restrict__ out2) {
    __shared__ u16 As[128 * 128];   // 32 KB, [px][k] bf16 (content pre-swizzled)

    int id = blockIdx.x;
    int sw = ((id & 7) << 9) | (id >> 3);   // XCD swizzle, 4096 = 8*512 bijective
    int b = sw >> 8;
    int ct = (sw >> 5) & 7;
    int pt = sw & 31;
    int n0 = pt * 128;
    int cb = ct * 128;
    int oi = cb >> 9;          // 0: out1/vt1/x1, 1: out2/vt2/x2
    int cbl = cb & 511;
    int t = threadIdx.x, w = t >> 6, l = t & 63;

    const float sc = scale_p[0];
    const u16* vt = (oi ? vt2 : vt1) + (size_t)b * C_ * K_;
    const float* xr = (oi ? x2 : x1) + (size_t)b * C_ * N_;
    float* op = (oi ? out2 : out1) + (size_t)b * C_ * N_;

    // async stage attn tile: granule gi = p*256+t; px = gi>>4, gp = gi&15;
    // source granule = gp ^ (px&15)  =>  read at 8*(g^(px&15)) returns granule g.
    const u16* ap = attnb + ((size_t)(b * N_ + n0)) * 128;
#pragma unroll
    for (int p = 0; p < 8; ++p) {
        int gi = p * 256 + t;
        int px = gi >> 4, gp = gi & 15;
        gload_lds16(ap + (size_t)px * 128 + (gp ^ (px & 15)) * 8,
                    &As[(p * 256 + w * 64) * 8]);
    }

    // vt A-frags (L2) + residual loads issued before the barrier (overlap staging)
    short8v vf[2][4];
#pragma unroll
    for (int mf = 0; mf < 2; ++mf)
#pragma unroll
        for (int kc = 0; kc < 4; ++kc)
            vf[mf][kc] = *(const short8v*)(vt + (size_t)(cbl + w * 32 + mf * 16 + (l & 15)) * K_ + kc * 32 + (l >> 4) * 8);

    float rs[2][4][8];
#pragma unroll
    for (int mf = 0; mf < 2; ++mf)
#pragma unroll
        for (int rg = 0; rg < 4; ++rg) {
            const float* rp = xr + (size_t)(cbl + w * 32 + mf * 16 + (l >> 4) * 4 + rg) * N_ + n0 + (l & 15);
#pragma unroll
            for (int nf = 0; nf < 8; ++nf)
                rs[mf][rg][nf] = rp[nf * 16];
        }
    __syncthreads();   // the only barrier (drains gload_lds)

    floatx4 o[2][8] = {};
#pragma unroll
    for (int kc = 0; kc < 4; ++kc) {
#pragma unroll
        for (int nf = 0; nf < 8; ++nf) {
            int row = nf * 16 + (l & 15);
            int g = kc * 4 + (l >> 4);
            short8v bb = *(const short8v*)&As[row * 128 + 8 * (g ^ (row & 15))];
#pragma unroll
            for (int mf = 0; mf < 2; ++mf)
                o[mf][nf] = __builtin_amdgcn_mfma_f32_16x16x32_bf16(vf[mf][kc], bb, o[mf][nf], 0, 0, 0);
        }
    }

#pragma unroll
    for (int mf = 0; mf < 2; ++mf)
#pragma unroll
        for (int rg = 0; rg < 4; ++rg) {
            float* wp = op + (size_t)(cbl + w * 32 + mf * 16 + (l >> 4) * 4 + rg) * N_ + n0 + (l & 15);
#pragma unroll
            for (int nf = 0; nf < 8; ++nf)
                wp[nf * 16] = sc * o[mf][nf][rg] + rs[mf][rg][nf];
        }
}

// ---------------------------------------------------------------------------
extern "C" void kernel_launch(void* const* d_in, const int* in_sizes, int n_in,
                              void* d_out, int out_size, void* d_ws, size_t ws_size,
                              hipStream_t stream) {
    const float* x1 = (const float*)d_in[0];
    const float* y1 = (const float*)d_in[1];
    const float* x2 = (const float*)d_in[2];
    const float* y2 = (const float*)d_in[3];
    const float* wq1 = (const float*)d_in[4];
    const float* bq1 = (const float*)d_in[5];
    const float* wq2 = (const float*)d_in[6];
    const float* bq2 = (const float*)d_in[7];
    const float* wk1 = (const float*)d_in[8];
    const float* bk1 = (const float*)d_in[9];
    const float* wk2 = (const float*)d_in[10];
    const float* bk2 = (const float*)d_in[11];
    const float* wv1 = (const float*)d_in[12];
    const float* bv1 = (const float*)d_in[13];
    const float* wv2 = (const float*)d_in[14];
    const float* bv2 = (const float*)d_in[15];
    const float* scale = (const float*)d_in[16];

    char* ws = (char*)d_ws;
    u16* y1b  = (u16*)(ws + 0);
    u16* y2b  = (u16*)(ws + 2097152);
    u16* wk1b = (u16*)(ws + 4194304);
    u16* wk2b = (u16*)(ws + 4456448);
    u16* wv1b = (u16*)(ws + 4718592);
    u16* wv2b = (u16*)(ws + 5242880);
    u16* wq1t = (u16*)(ws + 5767168);
    u16* wq2t = (u16*)(ws + 5898240);
    u16* k1b  = (u16*)(ws + 6029312);
    u16* k2b  = (u16*)(ws + 7077888);
    u16* kd   = (u16*)(ws + 8126464);
    u16* kkd1 = (u16*)(ws + 9175040);
    u16* kkd2 = (u16*)(ws + 11272192);
    u16* vt1  = (u16*)(ws + 13369344);
    u16* vt2  = (u16*)(ws + 15466496);
    float* ebd = (float*)(ws + 17563648);
    u16* attnb = (u16*)(ws + 17571840);   // 16 MB

    float* out1 = (float*)d_out;
    float* out2 = out1 + (size_t)B_ * C_ * N_;

    hipLaunchKernelGGL(conv_all, dim3(11776), dim3(256), 0, stream,
                       y1, y2, wk1, wk2, wv1, wv2, wq1, wq2,
                       y1b, y2b, wk1b, wk2b, wv1b, wv2b, wq1t, wq2t);
    hipLaunchKernelGGL(gemm_gkgv, dim3(768), dim3(64), 0, stream,
                       y1b, y2b, wk1b, wk2b, wv1b, wv2b, bk1, bk2, bv1, bv2,
                       k1b, k2b, vt1, vt2);
    hipLaunchKernelGGL(kd_sub, dim3(2048), dim3(256), 0, stream, k1b, k2b, kd);
    hipLaunchKernelGGL(ebd_k, dim3(8), dim3(256), 0, stream, kd, bq1, bq2, ebd);
    hipLaunchKernelGGL(gemm_gkk, dim3(2, 8, 32), dim3(64), 0, stream,
                       kd, wq1t, wq2t, kkd1, kkd2);
    hipLaunchKernelGGL(e_attn, dim3(512), dim3(256), 0, stream,
                       x1, x2, kkd1, kkd2, ebd, attnb);
    hipLaunchKernelGGL(pv_attn, dim3(4096), dim3(256), 0, stream,
                       x1, x2, vt1, vt2, attnb, scale, out1, out2);
}